// Round 3
// baseline (390.117 us; speedup 1.0000x reference)
//
#include <hip/hip_runtime.h>
#include <hip/hip_bf16.h>

// Problem constants
#define Bsz 65536
#define Sdim 256
#define Aag 8
#define Kk 10
#define ADdim 128

// Per-k slab: [key-net 43008B][agents-net 43008B][action-net 59392B] = 145408 B
// Net layout (16B chunks, XOR-swizzled): W1 64 x CPR chunks, W2 64x8, W3 16x8 (zero-padded rows)
// W1/W2 ROWS are stored in g-permuted order so MFMA C-layout == next layer's B-fragment layout.
#define SLAB_K_ELEMS 72704
#define NET_ELEMS 21504   // elems per 43008-byte net

typedef float f32x4 __attribute__((ext_vector_type(4)));
typedef __bf16 bf16x8 __attribute__((ext_vector_type(8)));

#define MFMA(a, b, cacc) __builtin_amdgcn_mfma_f32_16x16x32_bf16((a), (b), (cacc), 0, 0, 0)

// R5: native cast — gfx950 lowers fptrunc f32->bf16 to v_cvt_pk_bf16_f32 (HW RNE).
__device__ __forceinline__ __bf16 f2bf(float f) {
    return (__bf16)f;
}

__device__ __forceinline__ unsigned int pack_bf2(float a, float b) {
    union { unsigned short s[2]; unsigned int u; } cv;
    union { unsigned short s; __bf16 b; } x;
    x.b = f2bf(a); cv.s[0] = x.s;
    x.b = f2bf(b); cv.s[1] = x.s;
    return cv.u;
}

__device__ __forceinline__ bf16x8 cvt8(float4 lo, float4 hi) {
    bf16x8 v;
    v[0] = f2bf(lo.x); v[1] = f2bf(lo.y); v[2] = f2bf(lo.z); v[3] = f2bf(lo.w);
    v[4] = f2bf(hi.x); v[5] = f2bf(hi.y); v[6] = f2bf(hi.z); v[7] = f2bf(hi.w);
    return v;
}

// Hidden-neuron permutation: C-layout position n = mt*16 + q*4 + i holds original neuron g(n).
__device__ __forceinline__ int gperm(int n) {
    return ((n >> 5) << 5) + (((n >> 2) & 3) << 3) + (((n >> 4) & 1) << 2) + (n & 3);
}

// ---------------- prep: fp32 weights -> XOR-swizzled, row-permuted bf16 slabs ----------------
__global__ void prep_weights(const float* __restrict__ kW1, const float* __restrict__ aW1,
                             const float* __restrict__ cW1, const float* __restrict__ kW2,
                             const float* __restrict__ aW2, const float* __restrict__ cW2,
                             const float* __restrict__ kW3, const float* __restrict__ aW3,
                             const float* __restrict__ cW3, __bf16* __restrict__ out) {
    int gid = blockIdx.x * 256 + threadIdx.x;  // one thread per 16B chunk
    if (gid >= 90880) return;
    int k = gid / 9088;
    int r = gid - k * 9088;
    int t, cn;
    if (r < 2688)      { t = 0; cn = r; }
    else if (r < 5376) { t = 1; cn = r - 2688; }
    else               { t = 2; cn = r - 5376; }
    const int KN = (t == 2) ? 384 : 256;
    const int CPR = KN / 8;
    const float* W1 = (t == 0) ? kW1 : (t == 1) ? aW1 : cW1;
    const float* W2 = (t == 0) ? kW2 : (t == 1) ? aW2 : cW2;
    const float* W3 = (t == 0) ? kW3 : (t == 1) ? aW3 : cW3;
    const int rows3 = (t == 0) ? 1 : 8;
    int dstchunk;
    const float* src = nullptr;
    if (cn < 64 * CPR) {
        int n = cn / CPR, k8 = cn - n * CPR;              // n = permuted-space row
        src = W1 + ((size_t)(k * 64 + gperm(n))) * KN + k8 * 8;
        dstchunk = n * CPR + (k8 ^ (n & 7));
    } else if (cn < 64 * CPR + 512) {
        int c2 = cn - 64 * CPR;
        int n = c2 >> 3, k8 = c2 & 7;
        src = W2 + ((size_t)(k * 64 + gperm(n))) * 64 + k8 * 8;   // rows permuted, k-cols original
        dstchunk = 64 * CPR + n * 8 + (k8 ^ (n & 7));
    } else {
        int c3 = cn - 64 * CPR - 512;
        int n = c3 >> 3, k8 = c3 & 7;
        if (n < rows3) src = W3 + ((size_t)(k * rows3 + n)) * 64 + k8 * 8;  // unpermuted
        dstchunk = 64 * CPR + 512 + n * 8 + (k8 ^ (n & 7));
    }
    bf16x8 v;
#pragma unroll
    for (int e = 0; e < 8; ++e) v[e] = src ? f2bf(src[e]) : (__bf16)0.0f;
    *(bf16x8*)(out + (size_t)k * SLAB_K_ELEMS + t * NET_ELEMS + dstchunk * 8) = v;
}

// ---------------- async staging: slab -> LDS, 1KB per wave-instruction ----------------
__device__ __forceinline__ void stage(const __bf16* __restrict__ src, __bf16* dst,
                                      int nchunks, int wave, int lane) {
    const char* g = (const char*)src + lane * 16;
    for (int ci = wave; ci < nchunks; ci += 8) {
        __builtin_amdgcn_global_load_lds(
            (const __attribute__((address_space(1))) void*)(g + ci * 1024),
            (__attribute__((address_space(3))) void*)((char*)dst + ci * 1024), 16, 0, 0);
    }
}

// Build next layer's B-fragment (k-block kb) from this lane's own packed h words.
__device__ __forceinline__ bf16x8 frag_from_hp(const unsigned int (&hp)[4][2], int kb) {
    int4 u = {(int)hp[kb * 2][0], (int)hp[kb * 2][1], (int)hp[kb * 2 + 1][0], (int)hp[kb * 2 + 1][1]};
    return __builtin_bit_cast(bf16x8, u);
}

// ---------------- R6: fused key+agents nets (both KB=8, both consume only xf) ----------------
// Interleaving the two independent nets doubles the independent MFMA chains (8 -> 16/wave)
// and hides each net's layer-boundary relu/pack VALU under the other net's MFMAs.
// W = LDS region A base (key net); agents net at W + NET_ELEMS.
__device__ __forceinline__ void compute_fusedKA(
    const __bf16* __restrict__ W, const bf16x8 (&xf)[2][8],
    int q, int c, int k,
    const float* __restrict__ b1k, const float* __restrict__ b2k, const float* __restrict__ b3k,
    const float* __restrict__ b1a, const float* __restrict__ b2a, const float* __restrict__ b3a,
    float (&keyv)[2], float (&ag)[2][4]) {
    constexpr int CPR = 32;              // W1 chunks per row (KB=8)
    constexpr int W2O = 64 * CPR * 8;    // 16384 elems
    constexpr int W3O = W2O + 4096;      // 20480 elems
    const __bf16* Wa = W + NET_ELEMS;

    // ---- layer 1 (both nets) ----
    f32x4 accK[4][2], accA[4][2];
#pragma unroll
    for (int mt = 0; mt < 4; ++mt) {
        int base = ((mt >> 1) << 5) + (q << 3) + ((mt & 1) << 2);  // g-permuted bias index
        float4 bk = *(const float4*)(b1k + k * 64 + base);
        float4 ba = *(const float4*)(b1a + k * 64 + base);
        accK[mt][0] = {bk.x, bk.y, bk.z, bk.w}; accK[mt][1] = accK[mt][0];
        accA[mt][0] = {ba.x, ba.y, ba.z, ba.w}; accA[mt][1] = accA[mt][0];
    }
#pragma unroll
    for (int kb = 0; kb < 8; ++kb) {
        bf16x8 b0 = xf[0][kb];
        bf16x8 b1 = xf[1][kb];
#pragma unroll
        for (int mt = 0; mt < 4; ++mt) {
            int n = mt * 16 + c;
            int off = (n * CPR + ((kb * 4 + q) ^ (n & 7))) << 3;
            bf16x8 aK = *(const bf16x8*)(W + off);
            bf16x8 aA = *(const bf16x8*)(Wa + off);
            accK[mt][0] = MFMA(aK, b0, accK[mt][0]);
            accK[mt][1] = MFMA(aK, b1, accK[mt][1]);
            accA[mt][0] = MFMA(aA, b0, accA[mt][0]);
            accA[mt][1] = MFMA(aA, b1, accA[mt][1]);
        }
    }
    unsigned int hpK[2][4][2], hpA[2][4][2];
#pragma unroll
    for (int s = 0; s < 2; ++s)
#pragma unroll
        for (int mt = 0; mt < 4; ++mt) {
            hpK[s][mt][0] = pack_bf2(fmaxf(accK[mt][s][0], 0.f), fmaxf(accK[mt][s][1], 0.f));
            hpK[s][mt][1] = pack_bf2(fmaxf(accK[mt][s][2], 0.f), fmaxf(accK[mt][s][3], 0.f));
            hpA[s][mt][0] = pack_bf2(fmaxf(accA[mt][s][0], 0.f), fmaxf(accA[mt][s][1], 0.f));
            hpA[s][mt][1] = pack_bf2(fmaxf(accA[mt][s][2], 0.f), fmaxf(accA[mt][s][3], 0.f));
        }

    // ---- layer 2 (both nets) ----
    f32x4 acc2K[4][2], acc2A[4][2];
#pragma unroll
    for (int mt = 0; mt < 4; ++mt) {
        int base = ((mt >> 1) << 5) + (q << 3) + ((mt & 1) << 2);
        float4 bk = *(const float4*)(b2k + k * 64 + base);
        float4 ba = *(const float4*)(b2a + k * 64 + base);
        acc2K[mt][0] = {bk.x, bk.y, bk.z, bk.w}; acc2K[mt][1] = acc2K[mt][0];
        acc2A[mt][0] = {ba.x, ba.y, ba.z, ba.w}; acc2A[mt][1] = acc2A[mt][0];
    }
#pragma unroll
    for (int kb = 0; kb < 2; ++kb) {
        bf16x8 bhK0 = frag_from_hp(hpK[0], kb);
        bf16x8 bhK1 = frag_from_hp(hpK[1], kb);
        bf16x8 bhA0 = frag_from_hp(hpA[0], kb);
        bf16x8 bhA1 = frag_from_hp(hpA[1], kb);
#pragma unroll
        for (int mt = 0; mt < 4; ++mt) {
            int n = mt * 16 + c;
            int off2 = W2O + ((n * 8 + ((kb * 4 + q) ^ (n & 7))) << 3);
            bf16x8 a2K = *(const bf16x8*)(W + off2);
            bf16x8 a2A = *(const bf16x8*)(Wa + off2);
            acc2K[mt][0] = MFMA(a2K, bhK0, acc2K[mt][0]);
            acc2K[mt][1] = MFMA(a2K, bhK1, acc2K[mt][1]);
            acc2A[mt][0] = MFMA(a2A, bhA0, acc2A[mt][0]);
            acc2A[mt][1] = MFMA(a2A, bhA1, acc2A[mt][1]);
        }
    }
#pragma unroll
    for (int s = 0; s < 2; ++s)
#pragma unroll
        for (int mt = 0; mt < 4; ++mt) {
            hpK[s][mt][0] = pack_bf2(fmaxf(acc2K[mt][s][0], 0.f), fmaxf(acc2K[mt][s][1], 0.f));
            hpK[s][mt][1] = pack_bf2(fmaxf(acc2K[mt][s][2], 0.f), fmaxf(acc2K[mt][s][3], 0.f));
            hpA[s][mt][0] = pack_bf2(fmaxf(acc2A[mt][s][0], 0.f), fmaxf(acc2A[mt][s][1], 0.f));
            hpA[s][mt][1] = pack_bf2(fmaxf(acc2A[mt][s][2], 0.f), fmaxf(acc2A[mt][s][3], 0.f));
        }

    // ---- layer 3 (both nets; W3 zero-padded to 16 rows) ----
    f32x4 accK3[2], accA3[2];
    {
        float b3 = b3k[k];
        f32x4 zk = {0.f, 0.f, 0.f, 0.f};
        if (q == 0) zk[0] = b3;
        accK3[0] = zk; accK3[1] = zk;
        f32x4 za = {0.f, 0.f, 0.f, 0.f};
        if (q < 2) {
            float4 bv = *(const float4*)(b3a + k * 8 + q * 4);
            za = {bv.x, bv.y, bv.z, bv.w};
        }
        accA3[0] = za; accA3[1] = za;
    }
#pragma unroll
    for (int kb = 0; kb < 2; ++kb) {
        int off3 = W3O + ((c * 8 + ((kb * 4 + q) ^ (c & 7))) << 3);
        bf16x8 a3K = *(const bf16x8*)(W + off3);
        bf16x8 a3A = *(const bf16x8*)(Wa + off3);
#pragma unroll
        for (int s = 0; s < 2; ++s) {
            accK3[s] = MFMA(a3K, frag_from_hp(hpK[s], kb), accK3[s]);
            accA3[s] = MFMA(a3A, frag_from_hp(hpA[s], kb), accA3[s]);
        }
    }
    // ---- epilogues ----
#pragma unroll
    for (int s = 0; s < 2; ++s) {
        float v = __shfl(accK3[s][0], c, 64);  // key row 0 lives in lanes 0..15 reg 0
        keyv[s] = fabsf(v) + 1e-10f;
#pragma unroll
        for (int i = 0; i < 4; ++i) ag[s][i] = 1.f / (1.f + __expf(-accA3[s][i]));
    }
}

// ---------------- action net (KB=12, MODE-2 of the original template) ----------------
// Re-reads its extra 128 x-columns (actions) from global fp32 each call so the fragments
// are TRANSIENT (die after layer 1) instead of 32 permanently-live VGPRs (R3/R4 lesson).
__device__ __forceinline__ void compute_action(
    const __bf16* __restrict__ W, const bf16x8 (&xf)[2][8],
    const float* __restrict__ actions, int rowbase,
    int q, int c, int k,
    const float* __restrict__ b1p, const float* __restrict__ b2p, const float* __restrict__ b3p,
    const float (&keyv)[2], const float (&ag)[2][4], float (&outacc)[2][4]) {
    constexpr int KB = 12;
    constexpr int CPR = KB * 4;          // 48 W1 chunks per row
    constexpr int W2O = 64 * CPR * 8;    // elem offset of W2
    constexpr int W3O = W2O + 4096;      // elem offset of W3

    // transient action-x fragments; loads issue ~32 MFMAs before first use
    bf16x8 xa[2][4];
#pragma unroll
    for (int s = 0; s < 2; ++s) {
        const float* ap = actions + (size_t)(rowbase + s * 16 + c) * ADdim + q * 8;
#pragma unroll
        for (int kb = 0; kb < 4; ++kb)
            xa[s][kb] = cvt8(*(const float4*)(ap + kb * 32), *(const float4*)(ap + kb * 32 + 4));
    }

    // ---- layer 1 ----
    f32x4 acc[4][2];
#pragma unroll
    for (int mt = 0; mt < 4; ++mt) {
        int base = ((mt >> 1) << 5) + (q << 3) + ((mt & 1) << 2);
        float4 bv = *(const float4*)(b1p + k * 64 + base);
        acc[mt][0] = {bv.x, bv.y, bv.z, bv.w}; acc[mt][1] = acc[mt][0];
    }
#pragma unroll
    for (int kb = 0; kb < KB; ++kb) {
        bf16x8 b0 = (kb < 8) ? xf[0][kb] : xa[0][kb - 8];
        bf16x8 b1 = (kb < 8) ? xf[1][kb] : xa[1][kb - 8];
#pragma unroll
        for (int mt = 0; mt < 4; ++mt) {
            int n = mt * 16 + c;
            bf16x8 a = *(const bf16x8*)(W + ((n * CPR + ((kb * 4 + q) ^ (n & 7))) << 3));
            acc[mt][0] = MFMA(a, b0, acc[mt][0]);
            acc[mt][1] = MFMA(a, b1, acc[mt][1]);
        }
    }
    unsigned int hp[2][4][2];
#pragma unroll
    for (int s = 0; s < 2; ++s)
#pragma unroll
        for (int mt = 0; mt < 4; ++mt) {
            hp[s][mt][0] = pack_bf2(fmaxf(acc[mt][s][0], 0.f), fmaxf(acc[mt][s][1], 0.f));
            hp[s][mt][1] = pack_bf2(fmaxf(acc[mt][s][2], 0.f), fmaxf(acc[mt][s][3], 0.f));
        }

    // ---- layer 2 ----
    f32x4 acc2[4][2];
#pragma unroll
    for (int mt = 0; mt < 4; ++mt) {
        int base = ((mt >> 1) << 5) + (q << 3) + ((mt & 1) << 2);
        float4 bv = *(const float4*)(b2p + k * 64 + base);
        acc2[mt][0] = {bv.x, bv.y, bv.z, bv.w}; acc2[mt][1] = acc2[mt][0];
    }
#pragma unroll
    for (int kb = 0; kb < 2; ++kb) {
        bf16x8 bh0 = frag_from_hp(hp[0], kb);
        bf16x8 bh1 = frag_from_hp(hp[1], kb);
#pragma unroll
        for (int mt = 0; mt < 4; ++mt) {
            int n = mt * 16 + c;
            bf16x8 a2 = *(const bf16x8*)(W + W2O + ((n * 8 + ((kb * 4 + q) ^ (n & 7))) << 3));
            acc2[mt][0] = MFMA(a2, bh0, acc2[mt][0]);
            acc2[mt][1] = MFMA(a2, bh1, acc2[mt][1]);
        }
    }
#pragma unroll
    for (int s = 0; s < 2; ++s)
#pragma unroll
        for (int mt = 0; mt < 4; ++mt) {
            hp[s][mt][0] = pack_bf2(fmaxf(acc2[mt][s][0], 0.f), fmaxf(acc2[mt][s][1], 0.f));
            hp[s][mt][1] = pack_bf2(fmaxf(acc2[mt][s][2], 0.f), fmaxf(acc2[mt][s][3], 0.f));
        }

    // ---- layer 3 ----
    f32x4 acc3[2];
    {
        f32x4 z = {0.f, 0.f, 0.f, 0.f};
        if (q < 2) {
            float4 bv = *(const float4*)(b3p + k * 8 + q * 4);
            z = {bv.x, bv.y, bv.z, bv.w};
        }
        acc3[0] = z; acc3[1] = z;
    }
#pragma unroll
    for (int kb = 0; kb < 2; ++kb) {
        bf16x8 a3 = *(const bf16x8*)(W + W3O + ((c * 8 + ((kb * 4 + q) ^ (c & 7))) << 3));
#pragma unroll
        for (int s = 0; s < 2; ++s) acc3[s] = MFMA(a3, frag_from_hp(hp[s], kb), acc3[s]);
    }
    // ---- epilogue: combine ----
#pragma unroll
    for (int s = 0; s < 2; ++s)
#pragma unroll
        for (int i = 0; i < 4; ++i)
            outacc[s][i] += keyv[s] * ag[s][i] * (1.f / (1.f + __expf(-acc3[s][i])));
}

// ---------------- main fused kernel: 512 thr, grid 256 (1 block/CU) ----------------
// R6 layout: LDS region A = key+agents (86016 B), region B = action (59392 B), 145408 B total.
// 2 barriers/k (was 3); async prefetch preserved: stage B under compute-A, stage next-A under
// compute-action. VGPR budget at launch_bounds(512,2) is 256/lane; fused peak ~190.
__global__ __launch_bounds__(512, 2) void qplex_main(
    const float* __restrict__ states, const float* __restrict__ actions,
    const __bf16* __restrict__ wbf,
    const float* __restrict__ b1k, const float* __restrict__ b2k, const float* __restrict__ b3k,
    const float* __restrict__ b1a, const float* __restrict__ b2a, const float* __restrict__ b3a,
    const float* __restrict__ b1c, const float* __restrict__ b2c, const float* __restrict__ b3c,
    float* __restrict__ out) {
    __shared__ __bf16 WB[SLAB_K_ELEMS];  // 145408 B: [A: key||agents 43008 elems][B: action 29696]
    __bf16* RA = WB;
    __bf16* RB = WB + 2 * NET_ELEMS;

    const int tid = threadIdx.x;
    const int lane = tid & 63;
    const int wave = tid >> 6;
    const int q = lane >> 4;
    const int c = lane & 15;
    const int rowbase = blockIdx.x * 256 + wave * 32;

    // kick off staging of slab-0 key+agents before anything else
    stage(wbf, RA, 84, wave, lane);

    // ---- load this wave's 32 rows of states as B-fragments (lane c: row rowbase+s*16+c) ----
    bf16x8 xf[2][8];
#pragma unroll
    for (int s = 0; s < 2; ++s) {
        const float* srow = states + (size_t)(rowbase + s * 16 + c) * Sdim + q * 8;
#pragma unroll
        for (int kb = 0; kb < 8; ++kb)
            xf[s][kb] = cvt8(*(const float4*)(srow + kb * 32), *(const float4*)(srow + kb * 32 + 4));
    }

    float keyv[2];
    float ag[2][4];
    float outacc[2][4];
#pragma unroll
    for (int s = 0; s < 2; ++s) {
        keyv[s] = 0.f;
#pragma unroll
        for (int i = 0; i < 4; ++i) { ag[s][i] = 0.f; outacc[s][i] = 0.f; }
    }

    __syncthreads();  // drains slab-0 key+agents staging (vmcnt0 before barrier)

    for (int k = 0; k < Kk; ++k) {
        const __bf16* kslab = wbf + (size_t)k * SLAB_K_ELEMS;
        // --- fused key+agents (region A); prefetch action net -> region B ---
        stage(kslab + 2 * NET_ELEMS, RB, 58, wave, lane);
        compute_fusedKA(RA, xf, q, c, k, b1k, b2k, b3k, b1a, b2a, b3a, keyv, ag);
        __syncthreads();
        // --- action net (region B); prefetch next slab's key+agents -> region A ---
        if (k < Kk - 1) stage(kslab + SLAB_K_ELEMS, RA, 84, wave, lane);
        compute_action(RB, xf, actions, rowbase, q, c, k, b1c, b2c, b3c, keyv, ag, outacc);
        __syncthreads();
    }

    // ---- store: rows q*4+i are agents a (q<2), col c is batch ----
    if (q < 2) {
#pragma unroll
        for (int s = 0; s < 2; ++s) {
            int r = rowbase + s * 16 + c;
            float4 v = {outacc[s][0], outacc[s][1], outacc[s][2], outacc[s][3]};
            *(float4*)(out + (size_t)r * Aag + q * 4) = v;
        }
    }
}

extern "C" void kernel_launch(void* const* d_in, const int* in_sizes, int n_in,
                              void* d_out, int out_size, void* d_ws, size_t ws_size,
                              hipStream_t stream) {
    const float* states = (const float*)d_in[0];
    const float* actions = (const float*)d_in[1];
    const float* kW1 = (const float*)d_in[2];
    const float* kb1 = (const float*)d_in[3];
    const float* kW2 = (const float*)d_in[4];
    const float* kb2 = (const float*)d_in[5];
    const float* kW3 = (const float*)d_in[6];
    const float* kb3 = (const float*)d_in[7];
    const float* aW1 = (const float*)d_in[8];
    const float* ab1 = (const float*)d_in[9];
    const float* aW2 = (const float*)d_in[10];
    const float* ab2 = (const float*)d_in[11];
    const float* aW3 = (const float*)d_in[12];
    const float* ab3 = (const float*)d_in[13];
    const float* cW1 = (const float*)d_in[14];
    const float* cb1 = (const float*)d_in[15];
    const float* cW2 = (const float*)d_in[16];
    const float* cb2 = (const float*)d_in[17];
    const float* cW3 = (const float*)d_in[18];
    const float* cb3 = (const float*)d_in[19];
    float* out = (float*)d_out;
    __bf16* wbf = (__bf16*)d_ws;  // 1,454,080 bytes of scratch

    prep_weights<<<355, 256, 0, stream>>>(kW1, aW1, cW1, kW2, aW2, cW2, kW3, aW3, cW3, wbf);
    qplex_main<<<256, 512, 0, stream>>>(states, actions, wbf, kb1, kb2, kb3,
                                        ab1, ab2, ab3, cb1, cb2, cb3, out);
}